// Round 9
// baseline (269.786 us; speedup 1.0000x reference)
//
#include <hip/hip_runtime.h>
#include <hip/hip_bf16.h>

// SparseMSDeformableAttention MI355X — round 9.
// r8 post-mortem: sampler is L2-bound on gather bytes (VALU 44%, HBM 32%);
// GEMMs barrier-stall-bound at shallow K-depth.
//  - vproj stored bf16 (GEMM epilogue converts) -> sampler gathers halve to
//    16 B/lane short8, 16 points in one phase-2 pass.
//  - GEMM K-loop: register prefetch of next K-slab overlaps global latency
//    with MFMA+ds_read (vmcnt drain no longer at the barrier).
//  - off+attn GEMMs merged: N=384 (Wo,Wa contiguous), bias_cat built in cvt_k.

#define LQ    13294
#define NTOK  26588
#define CHUNK 3324        // ceil(NTOK/8) for XCD swizzle
#define NE    6806528     // NTOK*256

typedef unsigned short ushort_t;
typedef __attribute__((ext_vector_type(8))) short short8;
typedef __attribute__((ext_vector_type(4))) float float4_t;

__device__ __forceinline__ float b2f(ushort_t u) {
    return __uint_as_float(((unsigned int)u) << 16);
}
__device__ __forceinline__ ushort_t f2b(float f) {
    unsigned int x = __float_as_uint(f);
    return (ushort_t)((x + 0x7fffu + ((x >> 16) & 1u)) >> 16);   // RNE
}

// ---------------- bulk f32 -> bf16 convert + bias concat ----------------
__device__ __forceinline__ void cvt_seg(const float* __restrict__ s,
                                        ushort_t* __restrict__ d,
                                        int n4, int gid, int stride) {
    const float4_t* s4 = (const float4_t*)s;
    for (int i = gid; i < n4; i += stride) {
        float4_t f = s4[i];
        ushort4 o;
        o.x = f2b(f.x); o.y = f2b(f.y); o.z = f2b(f.z); o.w = f2b(f.w);
        *(ushort4*)(d + (long)i * 4) = o;
    }
}

__global__ __launch_bounds__(256) void cvt_k(
    const float* q, const float* v, const float* Wv, const float* Wo,
    const float* Wa, const float* Wout, const float* b_off, const float* b_attn,
    ushort_t* q_bf, ushort_t* v_bf, ushort_t* Wv_bf, ushort_t* Wo_bf,
    ushort_t* Wa_bf, ushort_t* Wout_bf, float* bias_cat)
{
    const int gid = blockIdx.x * 256 + threadIdx.x;
    const int stride = gridDim.x * 256;
    cvt_seg(q,    q_bf,    NE / 4,    gid, stride);
    cvt_seg(v,    v_bf,    NE / 4,    gid, stride);
    cvt_seg(Wv,   Wv_bf,   16384,     gid, stride);
    cvt_seg(Wo,   Wo_bf,   16384,     gid, stride);
    cvt_seg(Wa,   Wa_bf,   8192,      gid, stride);
    cvt_seg(Wout, Wout_bf, 16384,     gid, stride);
    if (gid < 96) {
        float4_t f = (gid < 64) ? ((const float4_t*)b_off)[gid]
                                : ((const float4_t*)b_attn)[gid - 64];
        ((float4_t*)bias_cat)[gid] = f;
    }
}

// ---------------- bf16 MFMA GEMM with register-prefetch pipeline ----------------
// C[M][N] = A[M][256] @ W[N][256]^T + bias (opt *zeta). 256 threads = 4 waves;
// tile 128(M) x 64(N), K-tile 32; LDS row stride 40 ushorts. Next K-slab is
// loaded into registers while MFMA/ds_read of the current slab runs.
template <bool OUT_BF>
__global__ __launch_bounds__(256) void gemm_mfma_k(
    const ushort_t* __restrict__ A,     // [M][256] bf16
    const ushort_t* __restrict__ W,     // [N][256] bf16
    const float* __restrict__ bias,     // [N] f32
    const float* __restrict__ zeta,     // [32] f32 or nullptr
    ushort_t* __restrict__ Cb,          // bf16 out (if OUT_BF)
    float* __restrict__ Cf,             // f32 out (else)
    int M, int N)
{
    __shared__ __align__(16) ushort_t As[128 * 40];
    __shared__ __align__(16) ushort_t Bs[64 * 40];
    const int tid = threadIdx.x;
    const int m0 = blockIdx.x * 128;
    const int n0 = blockIdx.y * 64;
    const int w  = tid >> 6;
    const int ln = tid & 63;
    const int sr = tid >> 2;            // staging row 0..63
    const int sc = (tid & 3) * 8;       // staging col {0,8,16,24}

    const int  mA0 = m0 + sr, mA1 = m0 + sr + 64;
    const bool ok0 = (mA0 < M), ok1 = (mA1 < M);
    const ushort_t* a0p = A + (long)mA0 * 256 + sc;
    const ushort_t* a1p = A + (long)mA1 * 256 + sc;
    const ushort_t* wpp = W + (long)(n0 + sr) * 256 + sc;

    float4_t acc[2][4] = {};
    short8 rA0 = {}, rA1 = {}, rB;

    if (ok0) rA0 = *(const short8*)(a0p);
    if (ok1) rA1 = *(const short8*)(a1p);
    rB = *(const short8*)(wpp);

    for (int k0 = 0; k0 < 256; k0 += 32) {
        // commit staged regs to LDS
        *(short8*)(As + sr * 40 + sc)        = rA0;
        *(short8*)(As + (sr + 64) * 40 + sc) = rA1;
        *(short8*)(Bs + sr * 40 + sc)        = rB;
        __syncthreads();

        // prefetch next K-slab (overlaps MFMA + ds_read below)
        if (k0 < 224) {
            if (ok0) rA0 = *(const short8*)(a0p + k0 + 32);
            if (ok1) rA1 = *(const short8*)(a1p + k0 + 32);
            rB = *(const short8*)(wpp + k0 + 32);
        }

        const int krow = (ln >> 4) * 8;
        short8 af[2], bfr[4];
        #pragma unroll
        for (int i = 0; i < 2; i++)
            af[i] = *(const short8*)(As + (w * 32 + i * 16 + (ln & 15)) * 40 + krow);
        #pragma unroll
        for (int j = 0; j < 4; j++)
            bfr[j] = *(const short8*)(Bs + (j * 16 + (ln & 15)) * 40 + krow);
        #pragma unroll
        for (int i = 0; i < 2; i++)
            #pragma unroll
            for (int j = 0; j < 4; j++)
                acc[i][j] = __builtin_amdgcn_mfma_f32_16x16x32_bf16(af[i], bfr[j], acc[i][j], 0, 0, 0);
        __syncthreads();
    }

    const int col = ln & 15;
    const int rq  = (ln >> 4) * 4;
    #pragma unroll
    for (int j = 0; j < 4; j++) {
        int n = n0 + j * 16 + col;
        float bz = bias[n];
        float zz = zeta ? zeta[n & 31] : 1.f;
        #pragma unroll
        for (int i = 0; i < 2; i++) {
            #pragma unroll
            for (int r = 0; r < 4; r++) {
                int m = m0 + w * 32 + i * 16 + rq + r;
                if (m < M) {
                    float vv = (acc[i][j][r] + bz) * zz;
                    if (OUT_BF) Cb[(long)m * N + n] = f2b(vv);
                    else        Cf[(long)m * N + n] = vv;
                }
            }
        }
    }
}

// ---------------- sampler: two-phase, bf16 gathers ----------------
// One block per token (XCD-swizzled), 512 threads = 8 waves.
// Phase 1: 128 threads = (head, point) -> softmax-scaled masked bilinear
//   weights + clamped corner row-offsets (bytes) -> LDS.
// Phase 2: lane (h = tid>>6, sp = ln>>2 point, g = ln&3 8-ch group):
//   4 x short8 gathers + 32 cvt+FMA; reduce over 16 point-slots (stride 4).
__global__ __launch_bounds__(512) void sample_k(
    const float* __restrict__ refp,      // [NTOK][4][2]
    const ushort_t* __restrict__ v,      // [NTOK][256] bf16 (b-major)
    const float* __restrict__ offattn,   // [NTOK][384]: 256 off + 128 logits
    ushort_t* __restrict__ outp)         // [NTOK][256] bf16
{
    __shared__ int   p_ofs[128][4];
    __shared__ float p_w[128][4];
    const int bid = blockIdx.x;
    const int t = (bid & 7) * CHUNK + (bid >> 3);
    if (t >= NTOK) return;             // uniform exit (before barrier)
    const int b = (t >= LQ) ? 1 : 0;
    const int tid = threadIdx.x;

    if (tid < 128) {
        const int h = tid >> 4, pi = tid & 15;
        const int lvl = pi >> 2;
        const int Wi  = (lvl == 0) ? 100 : (lvl == 1) ? 50 : (lvl == 2) ? 25 : 13;
        const int st  = (lvl == 0) ? 0 : (lvl == 1) ? 10000 : (lvl == 2) ? 12500 : 13125;
        const float Wf = (float)Wi;

        float lg = offattn[(long)t * 384 + 256 + h * 16 + pi];
        float smax = lg;
        #pragma unroll
        for (int d = 1; d < 16; d <<= 1) smax = fmaxf(smax, __shfl_xor(smax, d, 64));
        float ex = __expf(lg - smax);
        float sm = ex;
        #pragma unroll
        for (int d = 1; d < 16; d <<= 1) sm += __shfl_xor(sm, d, 64);
        const float a = ex / sm;

        float ox = offattn[(long)t * 384 + h * 32 + pi * 2];
        float oy = offattn[(long)t * 384 + h * 32 + pi * 2 + 1];
        float rx = refp[(long)t * 8 + lvl * 2];
        float ry = refp[(long)t * 8 + lvl * 2 + 1];

        float x = rx * Wf + ox - 0.5f;
        float y = ry * Wf + oy - 0.5f;
        float xf = floorf(x), yf = floorf(y);
        float wx = x - xf, wy = y - yf;
        int x0 = (int)xf, y0 = (int)yf;

        float mx0 = ((unsigned)x0       < (unsigned)Wi) ? (1.f - wx) : 0.f;
        float mx1 = ((unsigned)(x0 + 1) < (unsigned)Wi) ? wx         : 0.f;
        float my0 = ((unsigned)y0       < (unsigned)Wi) ? (1.f - wy) * a : 0.f;
        float my1 = ((unsigned)(y0 + 1) < (unsigned)Wi) ? wy * a         : 0.f;
        int x0c = min(max(x0, 0), Wi - 1);
        int x1c = min(max(x0 + 1, 0), Wi - 1);
        int y0c = min(max(y0, 0), Wi - 1);
        int y1c = min(max(y0 + 1, 0), Wi - 1);

        int r0 = st + y0c * Wi, r1 = st + y1c * Wi;
        p_ofs[tid][0] = (r0 + x0c) << 9;    // token-row byte offset (*256 ch *2 B)
        p_ofs[tid][1] = (r0 + x1c) << 9;
        p_ofs[tid][2] = (r1 + x0c) << 9;
        p_ofs[tid][3] = (r1 + x1c) << 9;
        p_w[tid][0] = mx0 * my0;
        p_w[tid][1] = mx1 * my0;
        p_w[tid][2] = mx0 * my1;
        p_w[tid][3] = mx1 * my1;
    }
    __syncthreads();

    const int h = tid >> 6, ln = tid & 63, sp = ln >> 2, g = ln & 3;
    const char* vb = (const char*)v + ((long)b * LQ * 256 + h * 32 + g * 8) * 2;

    const int task = h * 16 + sp;
    int4     o = *(const int4*)p_ofs[task];
    float4_t w = *(const float4_t*)p_w[task];
    ushort_t u0[8], u1[8], u2[8], u3[8];
    *(short8*)u0 = *(const short8*)(vb + o.x);
    *(short8*)u1 = *(const short8*)(vb + o.y);
    *(short8*)u2 = *(const short8*)(vb + o.z);
    *(short8*)u3 = *(const short8*)(vb + o.w);

    float acc[8];
    #pragma unroll
    for (int c = 0; c < 8; c++)
        acc[c] = w.x * b2f(u0[c]) + w.y * b2f(u1[c])
               + w.z * b2f(u2[c]) + w.w * b2f(u3[c]);

    // reduce over 16 point-slots (lanes sharing g are stride-4)
    #pragma unroll
    for (int d = 32; d >= 4; d >>= 1)
        #pragma unroll
        for (int c = 0; c < 8; c++)
            acc[c] += __shfl_down(acc[c], d, 64);

    if (sp == 0) {
        ushort_t ov[8];
        #pragma unroll
        for (int c = 0; c < 8; c++) ov[c] = f2b(acc[c]);
        *(short8*)(outp + (long)t * 256 + h * 32 + g * 8) = *(short8*)ov;
    }
}

extern "C" void kernel_launch(void* const* d_in, const int* in_sizes, int n_in,
                              void* d_out, int out_size, void* d_ws, size_t ws_size,
                              hipStream_t stream)
{
    // inputs: 0 query, 1 reference_points, 2 value, 3 spatial_shapes(int32),
    // 4 W_value, 5 b_value, 6 W_off, 7 b_off, 8 W_attn, 9 b_attn, 10 W_out, 11 b_out, 12 zeta
    char* ws = (char*)d_ws;
    ushort_t* vproj   = (ushort_t*)ws;                                // NE bf16
    float*    offattn = (float*)(ws + (long)NE * 2);                  // NTOK*384 f32
    char*     ws2     = ws + (long)NE * 2 + (long)NTOK * 384 * 4;
    ushort_t* v_bf    = (ushort_t*)ws2;                               // NE bf16
    ushort_t* outpre  = v_bf;                                         // overlay (v_bf dead)
    ushort_t* q_bf    = (ushort_t*)(ws2 + (long)NE * 2);              // NE bf16
    ushort_t* Wv_bf   = (ushort_t*)(ws2 + (long)NE * 4);
    ushort_t* Wo_bf   = Wv_bf + 65536;
    ushort_t* Wa_bf   = Wo_bf + 65536;   // contiguous with Wo -> merged N=384
    ushort_t* Wout_bf = Wa_bf + 32768;
    float*    bias_cat = (float*)(Wout_bf + 65536);                   // 384 f32

    dim3 blk(256);
    dim3 gm256(208, 4);   // N = 256
    dim3 gm384(208, 6);   // N = 384 (merged off+attn)

    cvt_k<<<1024, blk, 0, stream>>>(
        (const float*)d_in[0], (const float*)d_in[2], (const float*)d_in[4],
        (const float*)d_in[6], (const float*)d_in[8], (const float*)d_in[10],
        (const float*)d_in[7], (const float*)d_in[9],
        q_bf, v_bf, Wv_bf, Wo_bf, Wa_bf, Wout_bf, bias_cat);

    gemm_mfma_k<true><<<gm256, blk, 0, stream>>>(
        v_bf, Wv_bf, (const float*)d_in[5], (const float*)d_in[12],
        vproj, nullptr, NTOK, 256);

    gemm_mfma_k<false><<<gm384, blk, 0, stream>>>(
        q_bf, Wo_bf, bias_cat, nullptr,
        nullptr, offattn, NTOK, 384);

    sample_k<<<8 * CHUNK, 512, 0, stream>>>(
        (const float*)d_in[1], vproj, offattn, outpre);   // outpre overlays v_bf (dead)

    gemm_mfma_k<false><<<gm256, blk, 0, stream>>>(
        outpre, Wout_bf, (const float*)d_in[11], nullptr,
        nullptr, (float*)d_out, NTOK, 256);
}